// Round 1
// baseline (276.577 us; speedup 1.0000x reference)
//
#include <hip/hip_runtime.h>

#define NC 91
#define NB 32
#define HW (1024 * 1024)
#define PIX_PER_BLOCK 4096   // 256 threads * 4 int4 loads * 4 ints

__device__ __forceinline__ void proc_pixel(int x, int t, int* s_u, int* s_i) {
    // union = cnt_x + cnt_t - inter:
    //   x != t : union[x] += 1, union[t] += 1
    //   x == t : union[x] += 1, inter[x] += 1
    atomicAdd(&s_u[x], 1);
    if (x != t) {
        atomicAdd(&s_u[t], 1);
    } else {
        atomicAdd(&s_i[x], 1);
    }
}

__global__ __launch_bounds__(256) void hist_kernel(const int* __restrict__ x,
                                                   const int* __restrict__ t,
                                                   int* __restrict__ g_inter,
                                                   int* __restrict__ g_union) {
    __shared__ int s_i[NC];
    __shared__ int s_u[NC];
    const int tid = threadIdx.x;
    if (tid < NC) { s_i[tid] = 0; s_u[tid] = 0; }
    __syncthreads();

    const int b = blockIdx.y;
    const long base = (long)b * HW + (long)blockIdx.x * PIX_PER_BLOCK;
    const int4* __restrict__ x4 = (const int4*)(x + base);
    const int4* __restrict__ t4 = (const int4*)(t + base);

#pragma unroll
    for (int i = 0; i < 4; ++i) {
        int4 xv = x4[i * 256 + tid];
        int4 tv = t4[i * 256 + tid];
        proc_pixel(xv.x, tv.x, s_u, s_i);
        proc_pixel(xv.y, tv.y, s_u, s_i);
        proc_pixel(xv.z, tv.z, s_u, s_i);
        proc_pixel(xv.w, tv.w, s_u, s_i);
    }
    __syncthreads();

    if (tid < NC) {
        int u = s_u[tid];
        int in = s_i[tid];
        if (u)  atomicAdd(&g_union[b * NC + tid], u);
        if (in) atomicAdd(&g_inter[b * NC + tid], in);
    }
}

__global__ __launch_bounds__(64) void finalize_kernel(const int* __restrict__ g_inter,
                                                      const int* __restrict__ g_union,
                                                      const float* __restrict__ smooth,
                                                      float* __restrict__ out) {
    const int b = blockIdx.x;
    const int lane = threadIdx.x;  // 0..63
    const float s = smooth[0];
    float acc = 0.0f;
    for (int c = lane; c < NC; c += 64) {
        float in = (float)g_inter[b * NC + c];
        float un = (float)g_union[b * NC + c];
        acc += (in + s) / (un + s);
    }
#pragma unroll
    for (int off = 32; off > 0; off >>= 1)
        acc += __shfl_down(acc, off, 64);
    if (lane == 0) out[b] = acc / (float)NC;
}

extern "C" void kernel_launch(void* const* d_in, const int* in_sizes, int n_in,
                              void* d_out, int out_size, void* d_ws, size_t ws_size,
                              hipStream_t stream) {
    const int* x = (const int*)d_in[0];
    const int* t = (const int*)d_in[1];
    const float* smooth = (const float*)d_in[2];
    float* out = (float*)d_out;

    int* g_inter = (int*)d_ws;
    int* g_union = g_inter + NB * NC;

    hipMemsetAsync(d_ws, 0, 2 * NB * NC * sizeof(int), stream);

    dim3 grid(HW / PIX_PER_BLOCK, NB);  // 256 x 32 blocks
    hist_kernel<<<grid, 256, 0, stream>>>(x, t, g_inter, g_union);
    finalize_kernel<<<NB, 64, 0, stream>>>(g_inter, g_union, smooth, out);
}